// Round 8
// baseline (11975.139 us; speedup 1.0000x reference)
//
#include <hip/hip_runtime.h>

// ACT RNN, T=8192, IO=32, H=256, M=4, EPS=0.01. All f32 in/out.
// Round 16: sigmoid off the recurrence chain (round-15 base, 11.755 ms).
// Cycle model: ~1580cy/timestep = 870 VALU issue (512 = irreducible matvec)
// + ~510 LDS pipe (overlapped) + ~500 barrier/chain stalls. MFMA ruled out
// (N=1 col of 32 useful -> MFMA issue >= VALU issue). Partition space
// explored: 2r x 64c x 8 waves is the max(VALU,LDS) optimum. Remaining lever:
// the post-barrier serial tail. Changes:
//  - Halt decisions WITHOUT sigmoid: p0>0.99 <=> dot0 < -6.62936-bhp (const);
//    cum1+p1>0.99 <=> dot1 < log2(w0+.01)-log2(.99-w0)-bhp (rhs computed
//    off-path during round-1 matvec; exact algebra; NaN case benign).
//    p0 sigmoid stays off-path (for w0); p1 sigmoid only in rare branch.
//  - plds dot as v2f tree: 2 b128 + 3 pk_add + 1 add (was 7 scalar adds).
//  - Otherwise byte-identical to round 15: 2-row x 64-col lanes, quad
//    xor1+xor2 reduce, Z-linearity, quad-acc matvec (8-deep chain), 2-deep
//    U prefetch ring, 2 barriers/timestep, lgkmcnt-only barrier, L2E prefolds.
// ws = 8.45 MB (AccS aliases U in place; ws_size 16 MiB).

#define T_  8192
#define IO_ 32
#define H_  256

typedef __attribute__((ext_vector_type(2))) float v2f;

template<int CTRL>
__device__ __forceinline__ float dpp_addf(float x) {
    int xi = __builtin_bit_cast(int, x);
    int d = __builtin_amdgcn_update_dpp(xi, xi, CTRL, 0xF, 0xF, false);
    return x + __builtin_bit_cast(float, d);
}
// LDS-only barrier: flush DS ops, sync, do NOT drain vmcnt (global prefetch
// and fire-and-forget stores stay in flight).
__device__ __forceinline__ void bar_lds() {
    asm volatile("s_waitcnt lgkmcnt(0)\n\ts_barrier" ::: "memory");
    __builtin_amdgcn_sched_barrier(0);
}

// ---------------- k_prep: WxpT[io][h] = (Wx[:,:H]@Wp)^T, c = Wx[:,:H]@bp + b
__global__ void k_prep(const float* __restrict__ Wx,
                       const float* __restrict__ Wp,
                       const float* __restrict__ bp,
                       const float* __restrict__ b,
                       float* __restrict__ WxpT, float* __restrict__ cvec) {
    int h = blockIdx.x;           // 0..255
    int t = threadIdx.x;          // 0..63
    __shared__ float wxrow[H_];
    for (int j = t; j < H_; j += 64) wxrow[j] = Wx[h * (H_ + 1) + j];
    __syncthreads();
    if (t < IO_) {
        float acc = 0.0f;
        for (int j = 0; j < H_; ++j) acc += wxrow[j] * Wp[j * IO_ + t];
        WxpT[t * H_ + h] = acc;
    } else if (t == IO_) {
        float acc = b[h];
        for (int j = 0; j < H_; ++j) acc += wxrow[j] * bp[j];
        cvec[h] = acc;
    }
}

// ---------------- k_u: U[t][h] = (WxpT^T x_t + c) * 2*log2(e) ----------------
__global__ void k_u(const float* __restrict__ x,
                    const float* __restrict__ WxpT,
                    const float* __restrict__ cvec,
                    float* __restrict__ U) {
    int t0 = blockIdx.x * 8;
    int tid = threadIdx.x;        // 256
    __shared__ float xsf[8 * IO_];
    xsf[tid] = x[(size_t)t0 * IO_ + tid];
    __syncthreads();
    int h = tid;
    float base = cvec[h];
    const float L2E2 = 2.8853900817779268f;
    for (int tt = 0; tt < 8; ++tt) {
        float acc = base;
        #pragma unroll
        for (int io = 0; io < IO_; ++io)
            acc += WxpT[io * H_ + h] * xsf[tt * IO_ + io];
        U[(size_t)(t0 + tt) * H_ + h] = acc * L2E2;
    }
}

// ---------------- act_chain ----------------
__global__ __launch_bounds__(512, 2) void act_chain(
    const float* __restrict__ Ws,
    const float* __restrict__ Wx,
    const float* __restrict__ wh,
    const float* __restrict__ bh1,
    const float* __restrict__ h0,
    float* __restrict__ UAcc,
    float* __restrict__ cumArr,
    float* __restrict__ pc_out)
{
    __shared__ __align__(16) float sbuf[2][4 * 68];
    __shared__ __align__(16) float plds[2][8];

    const int tid = threadIdx.x;
    const int w   = tid >> 6;        // wave 0..7
    const int l   = tid & 63;
    const int rg  = l >> 2;          // row-group 0..15 (2 rows each)
    const int c   = l & 3;           // 64-col chunk 0..3
    const int rowbase = w * 32 + rg * 2;
    const int schunk  = rowbase >> 6;
    const int soff    = rowbase & 63;

    const float L2E  = 1.4426950408889634f;   // log2(e)
    const float L2E2 = 2.8853900817779268f;   // 2*log2(e)

    // Ws tile: 2 rows x 64 cols as v2f[2][32], prescaled by 2*log2(e)
    v2f wt[2][32];
    #pragma unroll
    for (int r = 0; r < 2; ++r) {
        const float4* src = (const float4*)(Ws + (size_t)(rowbase + r) * H_ + c * 64);
        #pragma unroll
        for (int q = 0; q < 16; ++q) {
            float4 f = src[q];
            wt[r][2 * q]     = (v2f){f.x * L2E2, f.y * L2E2};
            wt[r][2 * q + 1] = (v2f){f.z * L2E2, f.w * L2E2};
        }
    }

    v2f wl2, whp2;
    wl2.x  = Wx[(size_t)rowbase * (H_ + 1) + H_] * L2E2;       // first-step flag
    wl2.y  = Wx[(size_t)(rowbase + 1) * (H_ + 1) + H_] * L2E2;
    whp2.x = wh[rowbase]     * (-L2E);                          // sigmoid prescale
    whp2.y = wh[rowbase + 1] * (-L2E);
    const float bhp = -bh1[0] * L2E;
    const float thresh = 1.0f - 0.01f;
    // halt0 <=> p0 > 0.99 <=> dot0 + bhp < log2(0.01/0.99) <=> dot0 < hd0c
    const float hd0c = -6.6293566f - bhp;

    // matvec of a 64-float column chunk + quad reduce.
    // Quad accumulators per row: 8-deep dependent-fma chain.
    auto matvec = [&](const float4* sp) -> v2f {
        v2f a0[4] = {{0.f,0.f},{0.f,0.f},{0.f,0.f},{0.f,0.f}};
        v2f a1[4] = {{0.f,0.f},{0.f,0.f},{0.f,0.f},{0.f,0.f}};
        #pragma unroll
        for (int q = 0; q < 16; ++q) {
            float4 f = sp[q];
            v2f sa = (v2f){f.x, f.y};
            v2f sb = (v2f){f.z, f.w};
            a0[q & 1]       = a0[q & 1]       + wt[0][2 * q]     * sa;
            a0[2 + (q & 1)] = a0[2 + (q & 1)] + wt[0][2 * q + 1] * sb;
            a1[q & 1]       = a1[q & 1]       + wt[1][2 * q]     * sa;
            a1[2 + (q & 1)] = a1[2 + (q & 1)] + wt[1][2 * q + 1] * sb;
        }
        v2f t0 = (a0[0] + a0[1]) + (a0[2] + a0[3]);
        v2f t1 = (a1[0] + a1[1]) + (a1[2] + a1[3]);
        float y0 = t0.x + t0.y;
        float y1 = t1.x + t1.y;
        y0 = dpp_addf<0xB1>(y0); y0 = dpp_addf<0x4E>(y0);   // quad xor1, xor2
        y1 = dpp_addf<0xB1>(y1); y1 = dpp_addf<0x4E>(y1);
        return (v2f){y0, y1};
    };

    // prologue: zh = scaled Ws @ h0 (chunk read direct from global)
    v2f zh;
    {
        float4 hbuf[16];
        const float4* hp = (const float4*)(h0 + c * 64);
        #pragma unroll
        for (int q = 0; q < 16; ++q) hbuf[q] = hp[q];
        zh = matvec(hbuf);
    }

    float pc = 0.0f;
    // 2-deep U prefetch ring
    v2f un  = *(const v2f*)(UAcc + rowbase);
    v2f un1 = *(const v2f*)(UAcc + (T_ > 1 ? H_ : 0) + rowbase);
    v2f uw0 = un + wl2;                       // round-0 input add, precomputed

    // one ponder round: s = tanh(in); publish; halting partial; barrier;
    // plds read first (v2f tree dot -> dout, no sigmoid); matvec(s) -> z.
    auto round = [&](int WB, int PP, v2f in, v2f& z, float& dout) -> v2f {
        float e0 = __builtin_amdgcn_exp2f(in.x);
        float e1 = __builtin_amdgcn_exp2f(in.y);
        float s0 = __builtin_fmaf(-2.0f, __builtin_amdgcn_rcpf(e0 + 1.0f), 1.0f);
        float s1 = __builtin_fmaf(-2.0f, __builtin_amdgcn_rcpf(e1 + 1.0f), 1.0f);
        if (c == 0) *(v2f*)(&sbuf[WB][schunk * 68 + soff]) = (v2f){s0, s1};
        // halting partial (quad-uniform): ror4+ror8 over row-groups,
        // bcast15+bcast31 -> lane63 = wave total (verified round 8)
        float part = __builtin_fmaf(whp2.x, s0, whp2.y * s1);
        part = dpp_addf<0x124>(part);   // row_ror:4
        part = dpp_addf<0x128>(part);   // row_ror:8
        part = dpp_addf<0x142>(part);   // row_bcast15
        part = dpp_addf<0x143>(part);   // row_bcast31
        if (l == 63) plds[PP][w] = part;
        bar_lds();
        float4 pa = *(const float4*)(&plds[PP][0]);     // issue before matvec
        float4 pb = *(const float4*)(&plds[PP][4]);
        v2f t = ((v2f){pa.x, pa.y} + (v2f){pa.z, pa.w}) +
                ((v2f){pb.x, pb.y} + (v2f){pb.z, pb.w});
        dout = t.x + t.y;
        z = matvec((const float4*)(&sbuf[WB][c * 68]));
        return (v2f){s0, s1};
    };

    #pragma unroll 1
    for (int t = 0; t < T_; ++t) {
        const int tn2 = (t + 2 < T_) ? t + 2 : T_ - 1;
        const v2f un2 = *(const v2f*)(UAcc + (size_t)tn2 * H_ + rowbase);

        // rounds 0,1 unconditional straight-line
        v2f z0, z1;
        float d0, d1;
        v2f s0 = round(0, 0, zh + uw0, z0, d0);

        bool  halt0 = d0 < hd0c;                         // p0 > thresh, no sigmoid
        float p0 = __builtin_amdgcn_rcpf(
                       1.0f + __builtin_amdgcn_exp2f(d0 + bhp));  // off-path
        float w0 = halt0 ? 1.0f : p0;
        // halt1 <=> cum1+p1 > thresh <=> d1 < rhs1b (off-path transcendentals;
        // halt0 => q<0 => NaN => halt1=false, benign since still1=false)
        float rhs1b = __log2f(w0 + 0.01f) - __log2f(0.99f - w0) - bhp;

        v2f s1 = round(1, 1, z0 + un, z1, d1);

        bool  still1 = !halt0;
        bool  halt1  = d1 < rhs1b;
        float w1     = (still1 && halt1) ? (1.0f - w0) : 0.0f;
        v2f   accs   = w0 * s0 + w1 * s1;
        v2f   zacc   = w0 * z0 + w1 * z1;
        float cum    = w0 + w1;
        float nup    = still1 ? 2.0f : 1.0f;
        float rem    = halt0 ? 1.0f : (halt1 ? (1.0f - w0) : 0.0f);

        if (still1 && !halt1) {               // rare, block-uniform: rounds 2,3
            float p1 = __builtin_amdgcn_rcpf(
                           1.0f + __builtin_amdgcn_exp2f(d1 + bhp));
            float cum1 = w0;
            accs = w0 * s0 + p1 * s1;
            zacc = w0 * z0 + p1 * z1;
            float cum2 = cum1 + p1;
            v2f z2, z3;
            float d2, d3;
            v2f s2 = round(0, 0, z1 + un, z2, d2);
            float p2 = __builtin_amdgcn_rcpf(
                           1.0f + __builtin_amdgcn_exp2f(d2 + bhp));
            bool  halt2 = (cum2 + p2 > thresh);
            float w2    = halt2 ? 1.0f - cum2 : p2;
            float rem2  = halt2 ? 1.0f - cum2 : 0.0f;
            accs = accs + w2 * s2;
            zacc = zacc + w2 * z2;
            float cum3   = cum2 + w2;
            bool  still3 = !halt2;
            v2f s3 = round(1, 1, z2 + un, z3, d3);
            float w3 = still3 ? (1.0f - cum3) : 0.0f;   // n==3 forces halt
            accs = accs + w3 * s3;
            zacc = zacc + w3 * z3;
            rem  = rem2 + w3;
            cum  = cum3 + w3;
            nup  = still3 ? 4.0f : 3.0f;
        }

        pc = (pc + nup + rem) * (1.0f / (float)T_);
        zh = zacc;                            // Z(h') by linearity — no LDS trip
        if (c == 0) *(v2f*)(UAcc + (size_t)t * H_ + rowbase) = accs;
        if (tid == 0) cumArr[t] = cum;
        un  = un1;                            // advance prefetch ring
        un1 = un2;
        uw0 = un + wl2;                       // next round-0 add, off-path
    }
    if (tid == 0) pc_out[0] = pc;
}

// ---------------- k_out: ys[t] = Wo@acc_s[t] + cum[t]*bo ----------------
__global__ void k_out(const float* __restrict__ AccS,
                      const float* __restrict__ Wo,
                      const float* __restrict__ bo,
                      const float* __restrict__ cumArr,
                      float* __restrict__ ys) {
    int t0 = blockIdx.x * 8;
    int tid = threadIdx.x;   // 256
    __shared__ float wo[IO_ * 257];
    __shared__ float as[8 * 260];
    for (int i = tid; i < IO_ * H_; i += 256) {
        int o = i / H_, h = i % H_;
        wo[o * 257 + h] = Wo[i];
    }
    for (int i = tid; i < 8 * H_; i += 256) {
        int tt = i / H_, h = i % H_;
        as[tt * 260 + h] = AccS[(size_t)t0 * H_ + i];
    }
    __syncthreads();
    int tt = tid >> 5, o = tid & 31;
    float acc = cumArr[t0 + tt] * bo[o];
    #pragma unroll 4
    for (int h = 0; h < H_; ++h) acc += wo[o * 257 + h] * as[tt * 260 + h];
    ys[(size_t)(t0 + tt) * IO_ + o] = acc;
}

extern "C" void kernel_launch(void* const* d_in, const int* in_sizes, int n_in,
                              void* d_out, int out_size, void* d_ws, size_t ws_size,
                              hipStream_t stream) {
    const float* x  = (const float*)d_in[0];
    const float* h0 = (const float*)d_in[1];
    const float* Wp = (const float*)d_in[2];
    const float* bp = (const float*)d_in[3];
    const float* Wx = (const float*)d_in[4];
    const float* Ws = (const float*)d_in[5];
    const float* b  = (const float*)d_in[6];
    const float* wh = (const float*)d_in[7];
    const float* bh = (const float*)d_in[8];
    const float* Wo = (const float*)d_in[9];
    const float* bo = (const float*)d_in[10];
    float* out = (float*)d_out;   // f32: ys[8192*32] then pc

    char* ws = (char*)d_ws;
    float* WxpT = (float*)ws;                                    //  32 KB
    float* cvec = (float*)(ws + 32768);                          //   1 KB
    float* cumA = (float*)(ws + 33792);                          //  32 KB
    float* UAcc = (float*)(ws + 66560);                          //   8 MB f32
    // total ws use: 8.45 MB (AccS aliases UAcc in place)

    k_prep<<<H_, 64, 0, stream>>>(Wx, Wp, bp, b, WxpT, cvec);
    k_u<<<T_ / 8, 256, 0, stream>>>(x, WxpT, cvec, UAcc);
    act_chain<<<1, 512, 0, stream>>>(Ws, Wx, wh, bh, h0, UAcc, cumA,
                                     out + (size_t)T_ * IO_);
    k_out<<<T_ / 8, 256, 0, stream>>>(UAcc, Wo, bo, cumA, out);
}

// Round 9
// 11802.820 us; speedup vs baseline: 1.0146x; 1.0146x over previous
//
#include <hip/hip_runtime.h>

// ACT RNN, T=8192, IO=32, H=256, M=4, EPS=0.01. All f32 in/out.
// Round 17: FINAL — revert to the round-15 measured-best body (11.755 ms).
// Round-16's log2-threshold halt test regressed 1.4%: it shortened the serial
// chain ~25cy but added two quarter-rate v_log_f32 to a 60%-occupied issue
// pipe; at this operating point issue and latency trade ~1:1.
// Structure-floor arithmetic (9 variants, all 11.75-13.2 ms):
//   - VALU issue: 131072 MAC/timestep / 256 MAC/cy = 512cy + ~290cy overhead
//   - serial exchange: 2 x (publish -> barrier -> LDS rt -> fma chain) ~560cy
//   - measured ~1330cy/timestep; LDS-traffic 4x, barrier 3->2, chain 32->8,
//     branchless, heaters: all within noise. Exchange count 2/timestep is
//     minimal for this dataflow; MFMA rejected (N=1 -> dependent K-chain).
// Features: 2-row x 64-col lanes, quad xor1+xor2 reduce, Z-linearity (no h
// publication; 2 barriers/timestep), quad-acc matvec (8-deep chain), plds
// read hoisted before matvec, 2-deep U prefetch ring, L2E prefolds,
// lgkmcnt-only barrier, branchless rounds 0-1 + rare uniform rounds 2-3.
// ws = 8.45 MB (AccS aliases U in place; ws_size 16 MiB).

#define T_  8192
#define IO_ 32
#define H_  256

typedef __attribute__((ext_vector_type(2))) float v2f;

template<int CTRL>
__device__ __forceinline__ float dpp_addf(float x) {
    int xi = __builtin_bit_cast(int, x);
    int d = __builtin_amdgcn_update_dpp(xi, xi, CTRL, 0xF, 0xF, false);
    return x + __builtin_bit_cast(float, d);
}
// LDS-only barrier: flush DS ops, sync, do NOT drain vmcnt (global prefetch
// and fire-and-forget stores stay in flight).
__device__ __forceinline__ void bar_lds() {
    asm volatile("s_waitcnt lgkmcnt(0)\n\ts_barrier" ::: "memory");
    __builtin_amdgcn_sched_barrier(0);
}

// ---------------- k_prep: WxpT[io][h] = (Wx[:,:H]@Wp)^T, c = Wx[:,:H]@bp + b
__global__ void k_prep(const float* __restrict__ Wx,
                       const float* __restrict__ Wp,
                       const float* __restrict__ bp,
                       const float* __restrict__ b,
                       float* __restrict__ WxpT, float* __restrict__ cvec) {
    int h = blockIdx.x;           // 0..255
    int t = threadIdx.x;          // 0..63
    __shared__ float wxrow[H_];
    for (int j = t; j < H_; j += 64) wxrow[j] = Wx[h * (H_ + 1) + j];
    __syncthreads();
    if (t < IO_) {
        float acc = 0.0f;
        for (int j = 0; j < H_; ++j) acc += wxrow[j] * Wp[j * IO_ + t];
        WxpT[t * H_ + h] = acc;
    } else if (t == IO_) {
        float acc = b[h];
        for (int j = 0; j < H_; ++j) acc += wxrow[j] * bp[j];
        cvec[h] = acc;
    }
}

// ---------------- k_u: U[t][h] = (WxpT^T x_t + c) * 2*log2(e) ----------------
__global__ void k_u(const float* __restrict__ x,
                    const float* __restrict__ WxpT,
                    const float* __restrict__ cvec,
                    float* __restrict__ U) {
    int t0 = blockIdx.x * 8;
    int tid = threadIdx.x;        // 256
    __shared__ float xsf[8 * IO_];
    xsf[tid] = x[(size_t)t0 * IO_ + tid];
    __syncthreads();
    int h = tid;
    float base = cvec[h];
    const float L2E2 = 2.8853900817779268f;
    for (int tt = 0; tt < 8; ++tt) {
        float acc = base;
        #pragma unroll
        for (int io = 0; io < IO_; ++io)
            acc += WxpT[io * H_ + h] * xsf[tt * IO_ + io];
        U[(size_t)(t0 + tt) * H_ + h] = acc * L2E2;
    }
}

// ---------------- act_chain ----------------
__global__ __launch_bounds__(512, 2) void act_chain(
    const float* __restrict__ Ws,
    const float* __restrict__ Wx,
    const float* __restrict__ wh,
    const float* __restrict__ bh1,
    const float* __restrict__ h0,
    float* __restrict__ UAcc,
    float* __restrict__ cumArr,
    float* __restrict__ pc_out)
{
    __shared__ __align__(16) float sbuf[2][4 * 68];
    __shared__ __align__(16) float plds[2][8];

    const int tid = threadIdx.x;
    const int w   = tid >> 6;        // wave 0..7
    const int l   = tid & 63;
    const int rg  = l >> 2;          // row-group 0..15 (2 rows each)
    const int c   = l & 3;           // 64-col chunk 0..3
    const int rowbase = w * 32 + rg * 2;
    const int schunk  = rowbase >> 6;
    const int soff    = rowbase & 63;

    const float L2E  = 1.4426950408889634f;   // log2(e)
    const float L2E2 = 2.8853900817779268f;   // 2*log2(e)

    // Ws tile: 2 rows x 64 cols as v2f[2][32], prescaled by 2*log2(e)
    v2f wt[2][32];
    #pragma unroll
    for (int r = 0; r < 2; ++r) {
        const float4* src = (const float4*)(Ws + (size_t)(rowbase + r) * H_ + c * 64);
        #pragma unroll
        for (int q = 0; q < 16; ++q) {
            float4 f = src[q];
            wt[r][2 * q]     = (v2f){f.x * L2E2, f.y * L2E2};
            wt[r][2 * q + 1] = (v2f){f.z * L2E2, f.w * L2E2};
        }
    }

    v2f wl2, whp2;
    wl2.x  = Wx[(size_t)rowbase * (H_ + 1) + H_] * L2E2;       // first-step flag
    wl2.y  = Wx[(size_t)(rowbase + 1) * (H_ + 1) + H_] * L2E2;
    whp2.x = wh[rowbase]     * (-L2E);                          // sigmoid prescale
    whp2.y = wh[rowbase + 1] * (-L2E);
    const float bhp = -bh1[0] * L2E;
    const float thresh = 1.0f - 0.01f;

    // matvec of a 64-float column chunk + quad reduce.
    // Quad accumulators per row: 8-deep dependent-fma chain.
    auto matvec = [&](const float4* sp) -> v2f {
        v2f a0[4] = {{0.f,0.f},{0.f,0.f},{0.f,0.f},{0.f,0.f}};
        v2f a1[4] = {{0.f,0.f},{0.f,0.f},{0.f,0.f},{0.f,0.f}};
        #pragma unroll
        for (int q = 0; q < 16; ++q) {
            float4 f = sp[q];
            v2f sa = (v2f){f.x, f.y};
            v2f sb = (v2f){f.z, f.w};
            a0[q & 1]       = a0[q & 1]       + wt[0][2 * q]     * sa;
            a0[2 + (q & 1)] = a0[2 + (q & 1)] + wt[0][2 * q + 1] * sb;
            a1[q & 1]       = a1[q & 1]       + wt[1][2 * q]     * sa;
            a1[2 + (q & 1)] = a1[2 + (q & 1)] + wt[1][2 * q + 1] * sb;
        }
        v2f t0 = (a0[0] + a0[1]) + (a0[2] + a0[3]);
        v2f t1 = (a1[0] + a1[1]) + (a1[2] + a1[3]);
        float y0 = t0.x + t0.y;
        float y1 = t1.x + t1.y;
        y0 = dpp_addf<0xB1>(y0); y0 = dpp_addf<0x4E>(y0);   // quad xor1, xor2
        y1 = dpp_addf<0xB1>(y1); y1 = dpp_addf<0x4E>(y1);
        return (v2f){y0, y1};
    };

    // prologue: zh = scaled Ws @ h0 (chunk read direct from global)
    v2f zh;
    {
        float4 hbuf[16];
        const float4* hp = (const float4*)(h0 + c * 64);
        #pragma unroll
        for (int q = 0; q < 16; ++q) hbuf[q] = hp[q];
        zh = matvec(hbuf);
    }

    float pc = 0.0f;
    // 2-deep U prefetch ring
    v2f un  = *(const v2f*)(UAcc + rowbase);
    v2f un1 = *(const v2f*)(UAcc + (T_ > 1 ? H_ : 0) + rowbase);
    v2f uw0 = un + wl2;                       // round-0 input add, precomputed

    // one ponder round: s = tanh(in); publish; halting partial; barrier;
    // plds read first (halt chain overlaps matvec); matvec(s) -> z.
    auto round = [&](int WB, int PP, v2f in, v2f& z, float& p) -> v2f {
        float e0 = __builtin_amdgcn_exp2f(in.x);
        float e1 = __builtin_amdgcn_exp2f(in.y);
        float s0 = __builtin_fmaf(-2.0f, __builtin_amdgcn_rcpf(e0 + 1.0f), 1.0f);
        float s1 = __builtin_fmaf(-2.0f, __builtin_amdgcn_rcpf(e1 + 1.0f), 1.0f);
        if (c == 0) *(v2f*)(&sbuf[WB][schunk * 68 + soff]) = (v2f){s0, s1};
        // halting partial (quad-uniform): ror4+ror8 over row-groups,
        // bcast15+bcast31 -> lane63 = wave total (verified round 8)
        float part = __builtin_fmaf(whp2.x, s0, whp2.y * s1);
        part = dpp_addf<0x124>(part);   // row_ror:4
        part = dpp_addf<0x128>(part);   // row_ror:8
        part = dpp_addf<0x142>(part);   // row_bcast15
        part = dpp_addf<0x143>(part);   // row_bcast31
        if (l == 63) plds[PP][w] = part;
        bar_lds();
        float4 pa = *(const float4*)(&plds[PP][0]);     // issue before matvec
        float4 pb = *(const float4*)(&plds[PP][4]);     // reads: halt chain
        float dot = ((pa.x + pa.y) + (pa.z + pa.w)) +   // overlaps matvec
                    ((pb.x + pb.y) + (pb.z + pb.w));
        p = __builtin_amdgcn_rcpf(1.0f + __builtin_amdgcn_exp2f(dot + bhp));
        z = matvec((const float4*)(&sbuf[WB][c * 68]));
        return (v2f){s0, s1};
    };

    #pragma unroll 1
    for (int t = 0; t < T_; ++t) {
        const int tn2 = (t + 2 < T_) ? t + 2 : T_ - 1;
        const v2f un2 = *(const v2f*)(UAcc + (size_t)tn2 * H_ + rowbase);

        // rounds 0,1 unconditional straight-line
        v2f z0, z1;
        float p0, p1;
        v2f s0 = round(0, 0, zh + uw0, z0, p0);
        v2f s1 = round(1, 1, z0 + un,  z1, p1);

        bool  halt0  = p0 > thresh;
        float w0     = halt0 ? 1.0f : p0;
        bool  still1 = !halt0;
        float cum1   = w0;
        bool  halt1  = (cum1 + p1 > thresh);
        float w1     = still1 ? (halt1 ? 1.0f - cum1 : p1) : 0.0f;
        v2f   accs   = w0 * s0 + w1 * s1;
        v2f   zacc   = w0 * z0 + w1 * z1;
        float cum    = cum1 + w1;
        float nup    = still1 ? 2.0f : 1.0f;
        float rem    = halt0 ? 1.0f : (halt1 ? 1.0f - cum1 : 0.0f);

        if (still1 && !halt1) {               // rare, block-uniform: rounds 2,3
            v2f z2, z3;
            float p2, p3;
            v2f s2 = round(0, 0, z1 + un, z2, p2);
            bool  halt2 = (cum + p2 > thresh);
            float w2    = halt2 ? 1.0f - cum : p2;
            float rem2  = halt2 ? 1.0f - cum : 0.0f;
            accs = accs + w2 * s2;
            zacc = zacc + w2 * z2;
            float cum3   = cum + w2;
            bool  still3 = !halt2;
            v2f s3 = round(1, 1, z2 + un, z3, p3);
            float w3 = still3 ? (1.0f - cum3) : 0.0f;   // n==3 forces halt
            accs = accs + w3 * s3;
            zacc = zacc + w3 * z3;
            rem  = rem2 + w3;
            cum  = cum3 + w3;
            nup  = still3 ? 4.0f : 3.0f;
        }

        pc = (pc + nup + rem) * (1.0f / (float)T_);
        zh = zacc;                            // Z(h') by linearity — no LDS trip
        if (c == 0) *(v2f*)(UAcc + (size_t)t * H_ + rowbase) = accs;
        if (tid == 0) cumArr[t] = cum;
        un  = un1;                            // advance prefetch ring
        un1 = un2;
        uw0 = un + wl2;                       // next round-0 add, off-path
    }
    if (tid == 0) pc_out[0] = pc;
}

// ---------------- k_out: ys[t] = Wo@acc_s[t] + cum[t]*bo ----------------
__global__ void k_out(const float* __restrict__ AccS,
                      const float* __restrict__ Wo,
                      const float* __restrict__ bo,
                      const float* __restrict__ cumArr,
                      float* __restrict__ ys) {
    int t0 = blockIdx.x * 8;
    int tid = threadIdx.x;   // 256
    __shared__ float wo[IO_ * 257];
    __shared__ float as[8 * 260];
    for (int i = tid; i < IO_ * H_; i += 256) {
        int o = i / H_, h = i % H_;
        wo[o * 257 + h] = Wo[i];
    }
    for (int i = tid; i < 8 * H_; i += 256) {
        int tt = i / H_, h = i % H_;
        as[tt * 260 + h] = AccS[(size_t)t0 * H_ + i];
    }
    __syncthreads();
    int tt = tid >> 5, o = tid & 31;
    float acc = cumArr[t0 + tt] * bo[o];
    #pragma unroll 4
    for (int h = 0; h < H_; ++h) acc += wo[o * 257 + h] * as[tt * 260 + h];
    ys[(size_t)(t0 + tt) * IO_ + o] = acc;
}

extern "C" void kernel_launch(void* const* d_in, const int* in_sizes, int n_in,
                              void* d_out, int out_size, void* d_ws, size_t ws_size,
                              hipStream_t stream) {
    const float* x  = (const float*)d_in[0];
    const float* h0 = (const float*)d_in[1];
    const float* Wp = (const float*)d_in[2];
    const float* bp = (const float*)d_in[3];
    const float* Wx = (const float*)d_in[4];
    const float* Ws = (const float*)d_in[5];
    const float* b  = (const float*)d_in[6];
    const float* wh = (const float*)d_in[7];
    const float* bh = (const float*)d_in[8];
    const float* Wo = (const float*)d_in[9];
    const float* bo = (const float*)d_in[10];
    float* out = (float*)d_out;   // f32: ys[8192*32] then pc

    char* ws = (char*)d_ws;
    float* WxpT = (float*)ws;                                    //  32 KB
    float* cvec = (float*)(ws + 32768);                          //   1 KB
    float* cumA = (float*)(ws + 33792);                          //  32 KB
    float* UAcc = (float*)(ws + 66560);                          //   8 MB f32
    // total ws use: 8.45 MB (AccS aliases UAcc in place)

    k_prep<<<H_, 64, 0, stream>>>(Wx, Wp, bp, b, WxpT, cvec);
    k_u<<<T_ / 8, 256, 0, stream>>>(x, WxpT, cvec, UAcc);
    act_chain<<<1, 512, 0, stream>>>(Ws, Wx, wh, bh, h0, UAcc, cumA,
                                     out + (size_t)T_ * IO_);
    k_out<<<T_ / 8, 256, 0, stream>>>(UAcc, Wo, bo, cumA, out);
}